// Round 11
// baseline (116.017 us; speedup 1.0000x reference)
//
#include <hip/hip_runtime.h>
#include <hip/hip_bf16.h>

constexpr int B  = 8;
constexpr int N  = 1024;
constexpr int FI = 64;
constexpr int FO = 128;
constexpr int NH = 4;
constexpr float LOG2E = 1.4426950408889634f;

using short8 = __attribute__((ext_vector_type(8))) short;
using f32x4  = __attribute__((ext_vector_type(4))) float;

union I8 { int4 v[2]; int s[8]; };
union F8 { float4 v[2]; float s[8]; };

__device__ __forceinline__ unsigned bfpack(float a, float b) {
  __hip_bfloat162 r = __float22bfloat162_rn(make_float2(a, b));
  union { __hip_bfloat162 h; unsigned u; } c; c.h = r; return c.u;
}
__device__ __forceinline__ float bf2f(unsigned short u) {
  union { unsigned int b; float f; } c; c.b = (unsigned int)u << 16; return c.f;
}

// ---------------------------------------------------------------------------
// Kernel 0: mew[i][j] = adj ? bf16(ew) : -0.0  (sign bit = mask).
// ---------------------------------------------------------------------------
__global__ __launch_bounds__(256) void gat_mask(
    const int* __restrict__ adj, const float* __restrict__ ew,
    unsigned short* __restrict__ mew) {
  const size_t base = ((size_t)blockIdx.x * 256 + threadIdx.x) * 8;
  I8 aj; aj.v[0] = *(const int4*)(adj + base); aj.v[1] = *(const int4*)(adj + base + 4);
  F8 e;  e.v[0]  = *(const float4*)(ew + base); e.v[1]  = *(const float4*)(ew + base + 4);
  union { unsigned short u[8]; uint4 v; } o;
  #pragma unroll
  for (int u = 0; u < 8; ++u) {
    __hip_bfloat16 hb = __float2bfloat16(e.s[u]);
    unsigned short bits = *reinterpret_cast<unsigned short*>(&hb);
    o.u[u] = aj.s[u] ? bits : (unsigned short)0x8000;   // -0.0 when masked
  }
  *(uint4*)(mew + base) = o.v;
}

// ---------------------------------------------------------------------------
// Kernel 1: h = x@W. Emits es (row-major) + edt transposed [b][h][j] (both
// pre-scaled by log2e), and h in PRE-FRAGMENTED MFMA-B layout, bf16 hi/lo:
//   hfrag[b][ft(8)][s(32)][lane(64)][8]   (lane = n + 16*kq, j = s*32+kq*8+u)
// so attn's per-wave B-load is ONE contiguous 1KB segment per K-step.
// ---------------------------------------------------------------------------
__global__ __launch_bounds__(256, 2) void gat_proj(
    const float* __restrict__ x, const float* __restrict__ W,
    const float* __restrict__ a,
    unsigned short* __restrict__ h_hi, unsigned short* __restrict__ h_lo,
    float* __restrict__ es, float* __restrict__ edt) {
  __shared__ float xs[16 * FI];
  const int t = threadIdx.x;
  const int row0 = blockIdx.x * 16;
  for (int i = t; i < 16 * FI; i += 256) xs[i] = x[row0 * FI + i];
  const int f  = t & 127;
  const int rh = t >> 7;
  float wc[FI];
  #pragma unroll
  for (int k = 0; k < FI; ++k) wc[k] = W[k * FO + f];
  const int hh = f >> 5, d = f & 31;
  const float a_s = a[hh * 64 + d] * LOG2E;
  const float a_d = a[hh * 64 + 32 + d] * LOG2E;
  __syncthreads();
  float acc8[8];
  #pragma unroll
  for (int r = 0; r < 8; ++r) {
    const int lr = rh * 8 + r;
    const float4* xr = (const float4*)(xs + lr * FI);
    float acc = 0.f;
    #pragma unroll
    for (int kq = 0; kq < FI / 4; ++kq) {
      const float4 xv = xr[kq];
      acc += xv.x * wc[4*kq] + xv.y * wc[4*kq+1] + xv.z * wc[4*kq+2] + xv.w * wc[4*kq+3];
    }
    acc8[r] = acc;
    float ps = acc * a_s, pd = acc * a_d;
    #pragma unroll
    for (int off = 16; off; off >>= 1) {
      ps += __shfl_xor(ps, off, 64);
      pd += __shfl_xor(pd, off, 64);
    }
    const int row = row0 + lr;
    if (d == 0) {
      es[row * NH + hh] = ps;
      edt[((size_t)((row >> 10) * NH + hh)) * N + (row & 1023)] = pd;
    }
  }
  const int bb = row0 >> 10;
  const int jl = (row0 & 1023) + rh * 8;       // 8 consecutive j, 8-aligned
  union { unsigned short u16[8]; uint4 v; } hi, lo;
  #pragma unroll
  for (int r = 0; r < 8; ++r) {
    __hip_bfloat16 hb = __float2bfloat16(acc8[r]);
    hi.u16[r] = *reinterpret_cast<unsigned short*>(&hb);
    float res = acc8[r] - __bfloat162float(hb);
    __hip_bfloat16 lb = __float2bfloat16(res);
    lo.u16[r] = *reinterpret_cast<unsigned short*>(&lb);
  }
  // B-fragment address: ft = f>>4, n = f&15, s = jl>>5, kq = (jl>>3)&3
  const int ft = f >> 4, n = f & 15;
  const int sS = jl >> 5, kq2 = (jl >> 3) & 3;
  const size_t base = (size_t)bb * (FO * N)
                    + ((size_t)(ft * 32 + sS) * 64 + (n + 16 * kq2)) * 8;
  *(uint4*)(h_hi + base) = hi.v;
  *(uint4*)(h_lo + base) = lo.v;
}

// ---------------------------------------------------------------------------
// Kernel 2: attention out (+ dinv). 512 thr, 16-row tiles, 512 blocks.
// Fully-unrolled 2-stage software pipeline, ALL loads issued at body top:
//   ld_p1(c+2), ld_B(c+1)  [issue first: full P1+P2 (~300cyc) before the
//                           barrier's mandatory vmcnt(0) drain (m97)]
//   P1(c+1): exp from regs loaded last iter -> pew[(c+1)&1]; dpart += p*sgn
//   P2(c):   ds_read A-frags + MFMA, B already in registers
//   barrier
// Epilogue: dpart reduce -> dinv global; out = acc_sum * inv (R4-proven).
// ---------------------------------------------------------------------------
__global__ __launch_bounds__(512, 2) void gat_attn(
    const unsigned short* __restrict__ h_hi, const unsigned short* __restrict__ h_lo,
    const float* __restrict__ es, const float* __restrict__ edt,
    const unsigned short* __restrict__ mew,
    float* __restrict__ out, float* __restrict__ dinv) {
  __shared__ unsigned short pew[2][4 * 2048];
  __shared__ float dvl[64];
  const int t  = threadIdx.x;
  const int b  = blockIdx.x & 7;
  const int i0 = (blockIdx.x >> 3) << 4;
  // P1 ids
  const int il = t >> 5, jq = t & 31;
  const int gi = i0 + il;
  float esv[4];
  { const float4 e4 = *(const float4*)(es + ((size_t)b * N + gi) * NH);
    esv[0] = e4.x; esv[1] = e4.y; esv[2] = e4.z; esv[3] = e4.w; }
  // P2 ids
  const int lane = t & 63, wave = t >> 6;
  const int hh = wave & 3, nt2 = wave >> 2;
  const int m = lane & 15, kq = lane >> 4;
  const int ft = hh * 2 + nt2;
  const unsigned short* hb_hi = h_hi + (size_t)b * (FO * N) + (size_t)(ft * 32) * 512 + lane * 8;
  const unsigned short* hb_lo = h_lo + (size_t)b * (FO * N) + (size_t)(ft * 32) * 512 + lane * 8;
  f32x4 acc0 = {0.f,0.f,0.f,0.f}, acc1 = {0.f,0.f,0.f,0.f};
  f32x4 acc2 = {0.f,0.f,0.f,0.f}, acc3 = {0.f,0.f,0.f,0.f};
  float dpart[4] = {0.f, 0.f, 0.f, 0.f};

  struct P1R { uint2 mw; float4 ed[4]; };
  P1R r[2];
  short8 Bh[2][4], Bl[2][4];

  auto ld_p1 = [&](int c, P1R& R) {
    const int jb = c * 128 + jq * 4;
    R.mw = *(const uint2*)(mew + (size_t)gi * N + jb);
    #pragma unroll
    for (int h = 0; h < 4; ++h)
      R.ed[h] = *(const float4*)(edt + ((size_t)(b * NH + h)) * N + jb);
  };
  auto ld_B = [&](int c, short8* BH, short8* BL) {
    const size_t so = (size_t)c * 4 * 512;
    #pragma unroll
    for (int ks = 0; ks < 4; ++ks) {
      BH[ks] = *(const short8*)(hb_hi + so + (size_t)ks * 512);
      BL[ks] = *(const short8*)(hb_lo + so + (size_t)ks * 512);
    }
  };
  auto p1_compute = [&](int c, const P1R& R) {
    const int buf = c & 1;
    union { uint2 v; unsigned short u[4]; } mw; mw.v = R.mw;
    float edh[4][4];
    #pragma unroll
    for (int h = 0; h < 4; ++h) {
      edh[h][0] = R.ed[h].x; edh[h][1] = R.ed[h].y;
      edh[h][2] = R.ed[h].z; edh[h][3] = R.ed[h].w;
    }
    float pw[4][4];
    #pragma unroll
    for (int u = 0; u < 4; ++u) {
      const float mfa = bf2f((unsigned short)(mw.u[u] & 0x7fff));
      const float sgn = (mw.u[u] >> 15) ? 0.f : 1.f;
      #pragma unroll
      for (int h = 0; h < 4; ++h) {
        float e = esv[h] + edh[h][u];
        e = fmaxf(e, 0.2f * e);
        const float p = __builtin_amdgcn_exp2f(e);
        pw[h][u] = p * mfa;                     // masked: mfa=0 -> 0
        dpart[h] = fmaf(p, sgn, dpart[h]);
      }
    }
    const int g = jq >> 1, half = jq & 1;
    const int o = ((g * 16 + il) ^ (g & 7)) * 8 + half * 4;
    #pragma unroll
    for (int h = 0; h < 4; ++h) {
      uint2 pk = { bfpack(pw[h][0], pw[h][1]), bfpack(pw[h][2], pw[h][3]) };
      *(uint2*)(pew[buf] + h * 2048 + o) = pk;
    }
  };
  auto p2_step = [&](int c, const short8* BH, const short8* BL) {
    const int buf = c & 1;
    #pragma unroll
    for (int ks = 0; ks < 4; ++ks) {
      const int g2 = ks * 4 + kq;
      const int o2 = ((g2 * 16 + m) ^ (g2 & 7)) * 8;
      short8 afr;
      { uint4 tmp = *(const uint4*)(pew[buf] + hh * 2048 + o2);
        __builtin_memcpy(&afr, &tmp, 16); }
      if (ks & 1) {
        acc2 = __builtin_amdgcn_mfma_f32_16x16x32_bf16(afr, BH[ks], acc2, 0, 0, 0);
        acc3 = __builtin_amdgcn_mfma_f32_16x16x32_bf16(afr, BL[ks], acc3, 0, 0, 0);
      } else {
        acc0 = __builtin_amdgcn_mfma_f32_16x16x32_bf16(afr, BH[ks], acc0, 0, 0, 0);
        acc1 = __builtin_amdgcn_mfma_f32_16x16x32_bf16(afr, BL[ks], acc1, 0, 0, 0);
      }
    }
  };

  // ---- prologue: loads for chunks 0,1 + B(0) in flight, then P1(0) ----
  ld_p1(0, r[0]);
  ld_p1(1, r[1]);
  ld_B(0, Bh[0], Bl[0]);
  p1_compute(0, r[0]);
  __syncthreads();

  // ---- fully-unrolled pipeline ----
  #pragma unroll
  for (int c = 0; c < 8; ++c) {
    if (c + 1 < 8) ld_B(c + 1, Bh[(c + 1) & 1], Bl[(c + 1) & 1]);
    if (c + 2 < 8) ld_p1(c + 2, r[c & 1]);        // r[c&1] consumed last iter
    if (c + 1 < 8) p1_compute(c + 1, r[(c + 1) & 1]);
    p2_step(c, Bh[c & 1], Bl[c & 1]);
    if (c + 1 < 8) __syncthreads();
  }

  // ---- denominators: reduce over the 32-lane half sharing il ----
  #pragma unroll
  for (int h = 0; h < 4; ++h) {
    float v = dpart[h];
    v += __shfl_xor(v, 1, 64);  v += __shfl_xor(v, 2, 64);
    v += __shfl_xor(v, 4, 64);  v += __shfl_xor(v, 8, 64);
    v += __shfl_xor(v, 16, 64);
    if (jq == 0) dvl[il * NH + h] = v;
  }
  __syncthreads();
  if (t < 64) { const float dd = dvl[t]; dvl[t] = dd > 0.f ? 1.0f / dd : 0.f; }
  __syncthreads();
  if (t < 64) dinv[((size_t)b * N + i0) * NH + t] = dvl[t];
  // ---- out = acc_sum * inv  (fp32, R4-proven) ----
  #pragma unroll
  for (int reg = 0; reg < 4; ++reg) {
    const int row = kq * 4 + reg;              // D: col=lane&15, row=quad*4+reg
    const float inv = dvl[row * NH + hh];
    out[((size_t)b * N + i0 + row) * FO + hh * 32 + nt2 * 16 + m]
        = (acc0[reg] + acc1[reg] + acc2[reg] + acc3[reg]) * inv;
  }
}

// ---------------------------------------------------------------------------
// Kernel 3: avg. 2048 blocks (8/CU), 4 rows/block, one wave per row,
// no LDS/barriers. Recompute p, scale by dinv (R9-proven numerics),
// coalesced float4 writes. Write-bound: ~33.5 MB.
// ---------------------------------------------------------------------------
__global__ __launch_bounds__(256, 4) void gat_avg(
    const float* __restrict__ es, const float* __restrict__ edt,
    const unsigned short* __restrict__ mew, const float* __restrict__ dinv,
    float* __restrict__ avg) {
  const int t  = threadIdx.x;
  const int b  = blockIdx.x & 7;
  const int i0 = (blockIdx.x >> 3) << 2;
  const int il = t >> 6, jq = t & 63;
  const int gi = i0 + il;
  float esv[4], inv4[4];
  { const float4 e4 = *(const float4*)(es + ((size_t)b * N + gi) * NH);
    esv[0] = e4.x; esv[1] = e4.y; esv[2] = e4.z; esv[3] = e4.w; }
  { const float4 d4 = *(const float4*)(dinv + ((size_t)b * N + gi) * NH);
    inv4[0] = d4.x; inv4[1] = d4.y; inv4[2] = d4.z; inv4[3] = d4.w; }
  #pragma unroll
  for (int c = 0; c < 4; ++c) {
    const int jb = c * 256 + jq * 4;
    union { uint2 v; unsigned short u[4]; } mw;
    mw.v = *(const uint2*)(mew + (size_t)gi * N + jb);
    float edh[4][4];
    #pragma unroll
    for (int h = 0; h < 4; ++h) {
      const float4 e4 = *(const float4*)(edt + ((size_t)(b * NH + h)) * N + jb);
      edh[h][0] = e4.x; edh[h][1] = e4.y; edh[h][2] = e4.z; edh[h][3] = e4.w;
    }
    float4 r;
    float* rp = &r.x;
    #pragma unroll
    for (int u = 0; u < 4; ++u) {
      const float mfa = bf2f((unsigned short)(mw.u[u] & 0x7fff));
      float sv = 0.f;
      #pragma unroll
      for (int h = 0; h < 4; ++h) {
        float e = esv[h] + edh[h][u];
        e = fmaxf(e, 0.2f * e);
        sv += __builtin_amdgcn_exp2f(e) * inv4[h];
      }
      rp[u] = 0.25f * mfa * sv;            // masked: mfa=0 -> 0
    }
    *(float4*)(avg + ((size_t)b * N + gi) * N + jb) = r;
  }
}

// ---------------------------------------------------------------------------
extern "C" void kernel_launch(void* const* d_in, const int* in_sizes, int n_in,
                              void* d_out, int out_size, void* d_ws, size_t ws_size,
                              hipStream_t stream) {
  const float* x   = (const float*)d_in[0];
  const int*   adj = (const int*)d_in[1];
  const float* ewt = (const float*)d_in[2];
  const float* W   = (const float*)d_in[3];
  const float* a   = (const float*)d_in[4];

  float* out = (float*)d_out;                  // [B,N,128]
  float* avg = out + (size_t)B * N * FO;       // [B,N,N]

  unsigned short* hhi = (unsigned short*)d_ws;        // hfrag hi, 2 MB
  unsigned short* hlo = hhi + (size_t)B * FO * N;     // hfrag lo, 2 MB
  unsigned short* mew = hlo + (size_t)B * FO * N;     // [N,N] bf16 masked, 2 MB
  float* es   = (float*)(mew + (size_t)N * N);        // [B*N, 4]
  float* edt  = es + (size_t)B * N * NH;              // [B, 4, N]
  float* dnv  = edt + (size_t)B * NH * N;             // [B*N, 4]

  gat_mask<<<(N * N) / 2048, 256, 0, stream>>>(adj, ewt, mew);
  gat_proj<<<(B * N) / 16, 256, 0, stream>>>(x, W, a, hhi, hlo, es, edt);
  gat_attn<<<B * (N / 16), 512, 0, stream>>>(hhi, hlo, es, edt, mew, out, dnv);
  gat_avg<<<B * (N / 4), 256, 0, stream>>>(es, edt, mew, dnv, avg);
}

// Round 12
// 110.018 us; speedup vs baseline: 1.0545x; 1.0545x over previous
//
#include <hip/hip_runtime.h>
#include <hip/hip_bf16.h>

constexpr int B  = 8;
constexpr int N  = 1024;
constexpr int FI = 64;
constexpr int FO = 128;
constexpr int NH = 4;
constexpr float LOG2E = 1.4426950408889634f;

using short8 = __attribute__((ext_vector_type(8))) short;
using f32x4  = __attribute__((ext_vector_type(4))) float;

union I8 { int4 v[2]; int s[8]; };
union F8 { float4 v[2]; float s[8]; };

__device__ __forceinline__ unsigned bfpack(float a, float b) {
  __hip_bfloat162 r = __float22bfloat162_rn(make_float2(a, b));
  union { __hip_bfloat162 h; unsigned u; } c; c.h = r; return c.u;
}
__device__ __forceinline__ float bf2f(unsigned short u) {
  union { unsigned int b; float f; } c; c.b = (unsigned int)u << 16; return c.f;
}

// ---------------------------------------------------------------------------
// Kernel 1 (merged): blocks 0..511 = proj (h=x@W -> es/edt + hfrag hi/lo),
// blocks 512..1023 = mask (mew = adj ? bf16(ew) : -0.0). Independent work in
// one launch -> concurrent execution, one less dispatch.
// hfrag layout: [b][ft(8)][s(32)][lane(64)][8], lane=n+16*kq, j=s*32+kq*8+u.
// ---------------------------------------------------------------------------
__global__ __launch_bounds__(256, 2) void gat_prep(
    const float* __restrict__ x, const float* __restrict__ W,
    const float* __restrict__ a, const int* __restrict__ adj,
    const float* __restrict__ ew,
    unsigned short* __restrict__ h_hi, unsigned short* __restrict__ h_lo,
    float* __restrict__ es, float* __restrict__ edt,
    unsigned short* __restrict__ mew) {
  const int t = threadIdx.x;
  if (blockIdx.x >= 512) {        // ---- mask part ----
    const size_t base = ((size_t)(blockIdx.x - 512) * 256 + t) * 8;
    I8 aj; aj.v[0] = *(const int4*)(adj + base); aj.v[1] = *(const int4*)(adj + base + 4);
    F8 e;  e.v[0]  = *(const float4*)(ew + base); e.v[1]  = *(const float4*)(ew + base + 4);
    union { unsigned short u[8]; uint4 v; } o;
    #pragma unroll
    for (int u = 0; u < 8; ++u) {
      __hip_bfloat16 hb = __float2bfloat16(e.s[u]);
      unsigned short bits = *reinterpret_cast<unsigned short*>(&hb);
      o.u[u] = aj.s[u] ? bits : (unsigned short)0x8000;   // -0.0 when masked
    }
    *(uint4*)(mew + base) = o.v;
    return;
  }
  // ---- proj part ----
  __shared__ float xs[16 * FI];
  const int row0 = blockIdx.x * 16;
  for (int i = t; i < 16 * FI; i += 256) xs[i] = x[row0 * FI + i];
  const int f  = t & 127;
  const int rh = t >> 7;
  float wc[FI];
  #pragma unroll
  for (int k = 0; k < FI; ++k) wc[k] = W[k * FO + f];
  const int hh = f >> 5, d = f & 31;
  const float a_s = a[hh * 64 + d] * LOG2E;
  const float a_d = a[hh * 64 + 32 + d] * LOG2E;
  __syncthreads();
  float acc8[8];
  #pragma unroll
  for (int r = 0; r < 8; ++r) {
    const int lr = rh * 8 + r;
    const float4* xr = (const float4*)(xs + lr * FI);
    float acc = 0.f;
    #pragma unroll
    for (int kq = 0; kq < FI / 4; ++kq) {
      const float4 xv = xr[kq];
      acc += xv.x * wc[4*kq] + xv.y * wc[4*kq+1] + xv.z * wc[4*kq+2] + xv.w * wc[4*kq+3];
    }
    acc8[r] = acc;
    float ps = acc * a_s, pd = acc * a_d;
    #pragma unroll
    for (int off = 16; off; off >>= 1) {
      ps += __shfl_xor(ps, off, 64);
      pd += __shfl_xor(pd, off, 64);
    }
    const int row = row0 + lr;
    if (d == 0) {
      es[row * NH + hh] = ps;
      edt[((size_t)((row >> 10) * NH + hh)) * N + (row & 1023)] = pd;
    }
  }
  const int bb = row0 >> 10;
  const int jl = (row0 & 1023) + rh * 8;
  union { unsigned short u16[8]; uint4 v; } hi, lo;
  #pragma unroll
  for (int r = 0; r < 8; ++r) {
    __hip_bfloat16 hb = __float2bfloat16(acc8[r]);
    hi.u16[r] = *reinterpret_cast<unsigned short*>(&hb);
    float res = acc8[r] - __bfloat162float(hb);
    __hip_bfloat16 lb = __float2bfloat16(res);
    lo.u16[r] = *reinterpret_cast<unsigned short*>(&lb);
  }
  const int ft = f >> 4, n = f & 15;
  const int sS = jl >> 5, kq2 = (jl >> 3) & 3;
  const size_t base = (size_t)bb * (FO * N)
                    + ((size_t)(ft * 32 + sS) * 64 + (n + 16 * kq2)) * 8;
  *(uint4*)(h_hi + base) = hi.v;
  *(uint4*)(h_lo + base) = lo.v;
}

// ---------------------------------------------------------------------------
// Kernel 2: attention out + fused avg. 512 thr, 16-row tiles, 512 blocks.
// REGISTER-LEAN pipeline (R10/R11 post-mortem: struct-array double-buffers +
// full unroll pushed VGPR > 128 -> 1 block/CU; every barrier stalled the CU).
// Single B-buffer + single P1 prefetch + '#pragma unroll 1' + bounds (512,4)
// keep VGPR <= 128 so TWO blocks co-reside per CU.
//  body(c): P2(c) [B regs + pew LDS] -> ld_B(c+1) -> P1(c+1) -> ld_p1(c+2)
//           -> barrier.
// Epilogue: denom reduce -> inv; out = acc_sum*inv; then avg tail (R6-proven
// fp32 formula; mew/edt L1-hot; overlaps other blocks' main loops).
// ---------------------------------------------------------------------------
__global__ __launch_bounds__(512, 4) void gat_attn(
    const unsigned short* __restrict__ h_hi, const unsigned short* __restrict__ h_lo,
    const float* __restrict__ es, const float* __restrict__ edt,
    const unsigned short* __restrict__ mew,
    float* __restrict__ out, float* __restrict__ avg) {
  __shared__ unsigned short pew[2][4 * 2048];
  __shared__ float dvl[64];
  const int t  = threadIdx.x;
  const int b  = blockIdx.x & 7;
  const int i0 = (blockIdx.x >> 3) << 4;
  // P1 ids
  const int il = t >> 5, jq = t & 31;
  const int gi = i0 + il;
  float esv[4];
  { const float4 e4 = *(const float4*)(es + ((size_t)b * N + gi) * NH);
    esv[0] = e4.x; esv[1] = e4.y; esv[2] = e4.z; esv[3] = e4.w; }
  // P2 ids
  const int lane = t & 63, wave = t >> 6;
  const int hh = wave & 3, nt2 = wave >> 2;
  const int m = lane & 15, kq = lane >> 4;
  const int ft = hh * 2 + nt2;
  const unsigned short* hb_hi = h_hi + (size_t)b * (FO * N) + (size_t)(ft * 32) * 512 + lane * 8;
  const unsigned short* hb_lo = h_lo + (size_t)b * (FO * N) + (size_t)(ft * 32) * 512 + lane * 8;
  f32x4 acc0 = {0.f,0.f,0.f,0.f}, acc1 = {0.f,0.f,0.f,0.f};
  f32x4 acc2 = {0.f,0.f,0.f,0.f}, acc3 = {0.f,0.f,0.f,0.f};
  float dpart[4] = {0.f, 0.f, 0.f, 0.f};

  uint2  rmw;            // P1 prefetch regs (single set)
  float4 red[4];
  short8 Bh[4], Bl[4];   // B regs (single set)

  auto ld_p1 = [&](int c) {
    const int jb = c * 128 + jq * 4;
    rmw = *(const uint2*)(mew + (size_t)gi * N + jb);
    #pragma unroll
    for (int h = 0; h < 4; ++h)
      red[h] = *(const float4*)(edt + ((size_t)(b * NH + h)) * N + jb);
  };
  auto ld_B = [&](int c) {
    const size_t so = (size_t)c * 4 * 512;
    #pragma unroll
    for (int ks = 0; ks < 4; ++ks) {
      Bh[ks] = *(const short8*)(hb_hi + so + (size_t)ks * 512);
      Bl[ks] = *(const short8*)(hb_lo + so + (size_t)ks * 512);
    }
  };
  auto p1_compute = [&](int c) {
    const int buf = c & 1;
    union { uint2 v; unsigned short u[4]; } mw; mw.v = rmw;
    const int g = jq >> 1, half = jq & 1;
    const int o = ((g * 16 + il) ^ (g & 7)) * 8 + half * 4;
    #pragma unroll
    for (int up = 0; up < 2; ++up) {        // u-pairs: minimizes live temps
      float pk[4][2];
      #pragma unroll
      for (int uu = 0; uu < 2; ++uu) {
        const int u = up * 2 + uu;
        const float mfa = bf2f((unsigned short)(mw.u[u] & 0x7fff));
        const float sgn = (mw.u[u] >> 15) ? 0.f : 1.f;
        const float* ep = &red[0].x;
        #pragma unroll
        for (int h = 0; h < 4; ++h) {
          float e = esv[h] + (&red[h].x)[u];
          e = fmaxf(e, 0.2f * e);
          const float p = __builtin_amdgcn_exp2f(e);
          pk[h][uu] = p * mfa;
          dpart[h] = fmaf(p, sgn, dpart[h]);
        }
        (void)ep;
      }
      #pragma unroll
      for (int h = 0; h < 4; ++h)
        *(unsigned*)(pew[buf] + h * 2048 + o + up * 2) = bfpack(pk[h][0], pk[h][1]);
    }
  };
  auto p2_step = [&](int c) {
    const int buf = c & 1;
    #pragma unroll
    for (int ks = 0; ks < 4; ++ks) {
      const int g2 = ks * 4 + kq;
      const int o2 = ((g2 * 16 + m) ^ (g2 & 7)) * 8;
      short8 afr;
      { uint4 tmp = *(const uint4*)(pew[buf] + hh * 2048 + o2);
        __builtin_memcpy(&afr, &tmp, 16); }
      if (ks & 1) {
        acc2 = __builtin_amdgcn_mfma_f32_16x16x32_bf16(afr, Bh[ks], acc2, 0, 0, 0);
        acc3 = __builtin_amdgcn_mfma_f32_16x16x32_bf16(afr, Bl[ks], acc3, 0, 0, 0);
      } else {
        acc0 = __builtin_amdgcn_mfma_f32_16x16x32_bf16(afr, Bh[ks], acc0, 0, 0, 0);
        acc1 = __builtin_amdgcn_mfma_f32_16x16x32_bf16(afr, Bl[ks], acc1, 0, 0, 0);
      }
    }
  };

  // ---- prologue ----
  ld_B(0);
  ld_p1(0);
  p1_compute(0);
  ld_p1(1);
  __syncthreads();

  // ---- main loop: NOT unrolled (keeps single-buffer regs single) ----
  #pragma unroll 1
  for (int c = 0; c < 8; ++c) {
    p2_step(c);                       // consumes B(c) + pew[c&1]
    if (c + 1 < 8) {
      ld_B(c + 1);                    // refill B; ~1 chunk in flight before use
      p1_compute(c + 1);              // consumes r(c+1), writes pew[(c+1)&1]
      if (c + 2 < 8) ld_p1(c + 2);    // refill r
      __syncthreads();
    }
  }

  // ---- denominators: reduce over the 32-lane half sharing il ----
  #pragma unroll
  for (int h = 0; h < 4; ++h) {
    float v = dpart[h];
    v += __shfl_xor(v, 1, 64);  v += __shfl_xor(v, 2, 64);
    v += __shfl_xor(v, 4, 64);  v += __shfl_xor(v, 8, 64);
    v += __shfl_xor(v, 16, 64);
    if (jq == 0) dvl[il * NH + h] = v;
  }
  __syncthreads();
  if (t < 64) { const float dd = dvl[t]; dvl[t] = dd > 0.f ? 1.0f / dd : 0.f; }
  __syncthreads();
  // ---- out = acc_sum * inv (fp32, R4-proven) ----
  #pragma unroll
  for (int reg = 0; reg < 4; ++reg) {
    const int row = kq * 4 + reg;              // D: col=lane&15, row=quad*4+reg
    const float inv = dvl[row * NH + hh];
    out[((size_t)b * N + i0 + row) * FO + hh * 32 + nt2 * 16 + m]
        = (acc0[reg] + acc1[reg] + acc2[reg] + acc3[reg]) * inv;
  }
  // ---- fused avg tail (R6-proven fp32 formula; mew/edt L1-hot) ----
  float inv4[4];
  #pragma unroll
  for (int h = 0; h < 4; ++h) inv4[h] = dvl[il * NH + h];
  #pragma unroll 1
  for (int c = 0; c < 8; ++c) {
    const int jb = c * 128 + jq * 4;
    union { uint2 v; unsigned short u[4]; } mw;
    mw.v = *(const uint2*)(mew + (size_t)gi * N + jb);
    float4 ed4[4];
    #pragma unroll
    for (int h = 0; h < 4; ++h)
      ed4[h] = *(const float4*)(edt + ((size_t)(b * NH + h)) * N + jb);
    float4 r;
    float* rp = &r.x;
    #pragma unroll
    for (int u = 0; u < 4; ++u) {
      const float mfa = bf2f((unsigned short)(mw.u[u] & 0x7fff));
      float sv = 0.f;
      #pragma unroll
      for (int h = 0; h < 4; ++h) {
        float e = esv[h] + (&ed4[h].x)[u];
        e = fmaxf(e, 0.2f * e);
        sv += __builtin_amdgcn_exp2f(e) * inv4[h];
      }
      rp[u] = 0.25f * mfa * sv;            // masked: mfa=0 -> 0
    }
    *(float4*)(avg + ((size_t)b * N + gi) * N + jb) = r;
  }
}

// ---------------------------------------------------------------------------
extern "C" void kernel_launch(void* const* d_in, const int* in_sizes, int n_in,
                              void* d_out, int out_size, void* d_ws, size_t ws_size,
                              hipStream_t stream) {
  const float* x   = (const float*)d_in[0];
  const int*   adj = (const int*)d_in[1];
  const float* ewt = (const float*)d_in[2];
  const float* W   = (const float*)d_in[3];
  const float* a   = (const float*)d_in[4];

  float* out = (float*)d_out;                  // [B,N,128]
  float* avg = out + (size_t)B * N * FO;       // [B,N,N]

  unsigned short* hhi = (unsigned short*)d_ws;        // hfrag hi, 2 MB
  unsigned short* hlo = hhi + (size_t)B * FO * N;     // hfrag lo, 2 MB
  unsigned short* mew = hlo + (size_t)B * FO * N;     // [N,N] bf16 masked, 2 MB
  float* es   = (float*)(mew + (size_t)N * N);        // [B*N, 4]
  float* edt  = es + (size_t)B * N * NH;              // [B, 4, N]

  gat_prep<<<1024, 256, 0, stream>>>(x, W, a, adj, ewt, hhi, hlo, es, edt, mew);
  gat_attn<<<B * (N / 16), 512, 0, stream>>>(hhi, hlo, es, edt, mew, out, avg);
}